// Round 1
// baseline (201.187 us; speedup 1.0000x reference)
//
#include <hip/hip_runtime.h>
#include <math.h>

// Blocked parallel scan for a constant-coefficient 2-state affine recurrence.
// x_{t+1} = Trans x_t + XiCov dy_t + p0*cos(p1*t)*dt*[1,0];  out_t = Cout x_t.
// Chunks of L steps per thread; inter-chunk composition uses Trans^L (fp64).

constexpr int   TN  = 4000000;
constexpr float FDT = 1e-4f;
constexpr int   L   = 64;          // steps per chunk
constexpr int   K   = TN / L;      // 62500 chunks
constexpr int   G   = 250;         // chunks per group
constexpr int   NG  = K / G;       // 250 groups

struct Consts {
  float T00, T01, T10, T11;   // Trans
  float X00, X01, X10, X11;   // XiCov
  float C00, C01, C10, C11;   // Cout
  float p0, p1;
};

__device__ inline Consts make_consts(const float* __restrict__ A,
                                     const float* __restrict__ B,
                                     const float* __restrict__ E,
                                     const float* __restrict__ cov,
                                     const float* __restrict__ tp) {
  const float s2 = 1.41421356237309515f;  // sqrt(2)
  Consts c;
  float Xi[2][2];
  for (int i = 0; i < 2; ++i)
    for (int j = 0; j < 2; ++j)
      Xi[i][j] = (E[i*2+j] - (cov[i*2+0]*B[0*2+j] + cov[i*2+1]*B[1*2+j])) / s2;
  float XiC[2][2];
  for (int i = 0; i < 2; ++i)
    for (int j = 0; j < 2; ++j)
      XiC[i][j] = Xi[i][0]*(-s2*B[j*2+0]) + Xi[i][1]*(-s2*B[j*2+1]);
  c.T00 = 1.0f + (A[0] - XiC[0][0]) * FDT;
  c.T01 =        (A[1] - XiC[0][1]) * FDT;
  c.T10 =        (A[2] - XiC[1][0]) * FDT;
  c.T11 = 1.0f + (A[3] - XiC[1][1]) * FDT;
  c.X00 = Xi[0][0]; c.X01 = Xi[0][1]; c.X10 = Xi[1][0]; c.X11 = Xi[1][1];
  // Cout[i][j] = -sqrt2 * B[j][i] * dt
  c.C00 = -s2 * B[0] * FDT;
  c.C01 = -s2 * B[2] * FDT;
  c.C10 = -s2 * B[1] * FDT;
  c.C11 = -s2 * B[3] * FDT;
  c.p0 = tp[0]; c.p1 = tp[1];
  return c;
}

__device__ inline void step(float& x0, float& x1, float t, float a, float b,
                            const Consts& c) {
  float u0 = fmaf(c.X00, a, fmaf(c.X01, b, c.p0 * __cosf(c.p1 * t) * FDT));
  float u1 = fmaf(c.X10, a, c.X11 * b);
  float n0 = fmaf(c.T00, x0, fmaf(c.T01, x1, u0));
  float n1 = fmaf(c.T10, x0, fmaf(c.T11, x1, u1));
  x0 = n0; x1 = n1;
}

__device__ inline void dmatmul(const double* a, const double* b, double* o) {
  o[0] = a[0]*b[0] + a[1]*b[2];
  o[1] = a[0]*b[1] + a[1]*b[3];
  o[2] = a[2]*b[0] + a[3]*b[2];
  o[3] = a[2]*b[1] + a[3]*b[3];
}

// P = Trans^L (L = 64 = 2^6), fp64
__device__ inline void transPL(const Consts& c, double* P) {
  double M[4] = {(double)c.T00, (double)c.T01, (double)c.T10, (double)c.T11};
  for (int s = 0; s < 6; ++s) {
    double t[4]; dmatmul(M, M, t);
    M[0] = t[0]; M[1] = t[1]; M[2] = t[2]; M[3] = t[3];
  }
  P[0] = M[0]; P[1] = M[1]; P[2] = M[2]; P[3] = M[3];
}

// Phase 1: per-chunk offsets from zero start (fp32, mirrors reference math)
__global__ void __launch_bounds__(256)
kA(const float* __restrict__ seq, const float* __restrict__ A,
   const float* __restrict__ B, const float* __restrict__ E,
   const float* __restrict__ cov, const float* __restrict__ tp,
   float* __restrict__ cout_) {
  int k = blockIdx.x * blockDim.x + threadIdx.x;
  if (k >= K) return;
  Consts c = make_consts(A, B, E, cov, tp);
  const float4* p = (const float4*)(seq + (size_t)3 * L * k);  // 768B-aligned
  float x0 = 0.f, x1 = 0.f;
  #pragma unroll 4
  for (int q = 0; q < L / 4; ++q) {
    float4 fa = p[3*q+0], fb = p[3*q+1], fc = p[3*q+2];
    step(x0, x1, fa.x, fa.y, fa.z, c);
    step(x0, x1, fa.w, fb.x, fb.y, c);
    step(x0, x1, fb.z, fb.w, fc.x, c);
    step(x0, x1, fc.y, fc.z, fc.w, c);
  }
  cout_[2*k]   = x0;
  cout_[2*k+1] = x1;
}

// Phase 2a: per-group offsets (compose G chunk maps, fp64)
__global__ void __launch_bounds__(256)
kB(const float* __restrict__ A, const float* __restrict__ B,
   const float* __restrict__ E, const float* __restrict__ cov,
   const float* __restrict__ tp, const float* __restrict__ cin,
   double* __restrict__ Cg) {
  int g = blockIdx.x * blockDim.x + threadIdx.x;
  if (g >= NG) return;
  Consts c = make_consts(A, B, E, cov, tp);
  double P[4]; transPL(c, P);
  double y0 = 0.0, y1 = 0.0;
  for (int j = 0; j < G; ++j) {
    const float* cj = cin + 2 * ((size_t)g * G + j);
    double t0 = P[0]*y0 + P[1]*y1 + (double)cj[0];
    double t1 = P[2]*y0 + P[3]*y1 + (double)cj[1];
    y0 = t0; y1 = t1;
  }
  Cg[2*g]   = y0;
  Cg[2*g+1] = y1;
}

// Phase 2b: sequential scan over groups (Q = P^G), single thread
__global__ void
kC(const float* __restrict__ A, const float* __restrict__ B,
   const float* __restrict__ E, const float* __restrict__ cov,
   const float* __restrict__ tp, const float* __restrict__ ini,
   const double* __restrict__ Cg, double* __restrict__ Yg) {
  if (blockIdx.x != 0 || threadIdx.x != 0) return;
  Consts c = make_consts(A, B, E, cov, tp);
  double P[4]; transPL(c, P);
  // Q = P^G by square-and-multiply
  double Q[4] = {1.0, 0.0, 0.0, 1.0};
  double Bse[4] = {P[0], P[1], P[2], P[3]};
  int e = G;
  while (e) {
    if (e & 1) { double t[4]; dmatmul(Q, Bse, t); Q[0]=t[0]; Q[1]=t[1]; Q[2]=t[2]; Q[3]=t[3]; }
    double t2[4]; dmatmul(Bse, Bse, t2);
    Bse[0]=t2[0]; Bse[1]=t2[1]; Bse[2]=t2[2]; Bse[3]=t2[3];
    e >>= 1;
  }
  double y0 = (double)ini[0], y1 = (double)ini[1];
  for (int g = 0; g < NG; ++g) {
    Yg[2*g]   = y0;
    Yg[2*g+1] = y1;
    double t0 = Q[0]*y0 + Q[1]*y1 + Cg[2*g];
    double t1 = Q[2]*y0 + Q[3]*y1 + Cg[2*g+1];
    y0 = t0; y1 = t1;
  }
}

// Phase 2c: expand group starts to per-chunk start states
__global__ void __launch_bounds__(256)
kD(const float* __restrict__ A, const float* __restrict__ B,
   const float* __restrict__ E, const float* __restrict__ cov,
   const float* __restrict__ tp, const float* __restrict__ cin,
   const double* __restrict__ Yg, float* __restrict__ X) {
  int g = blockIdx.x * blockDim.x + threadIdx.x;
  if (g >= NG) return;
  Consts c = make_consts(A, B, E, cov, tp);
  double P[4]; transPL(c, P);
  double y0 = Yg[2*g], y1 = Yg[2*g+1];
  for (int j = 0; j < G; ++j) {
    size_t k = (size_t)g * G + j;
    X[2*k]   = (float)y0;
    X[2*k+1] = (float)y1;
    double t0 = P[0]*y0 + P[1]*y1 + (double)cin[2*k];
    double t1 = P[2]*y0 + P[3]*y1 + (double)cin[2*k+1];
    y0 = t0; y1 = t1;
  }
}

// Phase 3: re-run chunks from their true start states, emit outputs
__global__ void __launch_bounds__(256)
kE(const float* __restrict__ seq, const float* __restrict__ A,
   const float* __restrict__ B, const float* __restrict__ E,
   const float* __restrict__ cov, const float* __restrict__ tp,
   const float* __restrict__ X, float* __restrict__ out) {
  int k = blockIdx.x * blockDim.x + threadIdx.x;
  if (k >= K) return;
  Consts c = make_consts(A, B, E, cov, tp);
  const float4* p  = (const float4*)(seq + (size_t)3 * L * k);
  float4*       op = (float4*)(out + (size_t)2 * L * k);   // 512B-aligned
  float x0 = X[2*k], x1 = X[2*k+1];
  #pragma unroll 4
  for (int q = 0; q < L / 4; ++q) {
    float4 fa = p[3*q+0], fb = p[3*q+1], fc = p[3*q+2];
    float4 oA, oB;
    oA.x = fmaf(c.C00, x0, c.C01 * x1); oA.y = fmaf(c.C10, x0, c.C11 * x1);
    step(x0, x1, fa.x, fa.y, fa.z, c);
    oA.z = fmaf(c.C00, x0, c.C01 * x1); oA.w = fmaf(c.C10, x0, c.C11 * x1);
    step(x0, x1, fa.w, fb.x, fb.y, c);
    oB.x = fmaf(c.C00, x0, c.C01 * x1); oB.y = fmaf(c.C10, x0, c.C11 * x1);
    step(x0, x1, fb.z, fb.w, fc.x, c);
    oB.z = fmaf(c.C00, x0, c.C01 * x1); oB.w = fmaf(c.C10, x0, c.C11 * x1);
    step(x0, x1, fc.y, fc.z, fc.w, c);
    op[2*q]   = oA;
    op[2*q+1] = oB;
  }
}

extern "C" void kernel_launch(void* const* d_in, const int* in_sizes, int n_in,
                              void* d_out, int out_size, void* d_ws, size_t ws_size,
                              hipStream_t stream) {
  const float* seq = (const float*)d_in[0];   // (1, T, 3)
  const float* A   = (const float*)d_in[1];
  const float* B   = (const float*)d_in[2];
  // d_in[3] = D, unused by the reference step
  const float* E   = (const float*)d_in[4];
  const float* cov = (const float*)d_in[5];
  const float* tp  = (const float*)d_in[6];
  const float* ini = (const float*)d_in[7];
  float* out = (float*)d_out;

  // workspace layout (needs ~1.01 MB)
  float*  c  = (float*)d_ws;                         // 2*K floats  = 500000 B
  float*  X  = c + 2 * (size_t)K;                    // 2*K floats  = 500000 B
  double* Cg = (double*)((char*)d_ws + 1000000);     // 2*NG doubles
  double* Yg = Cg + 2 * NG;                          // 2*NG doubles

  int blk = (K + 255) / 256;  // 245
  kA<<<blk, 256, 0, stream>>>(seq, A, B, E, cov, tp, c);
  kB<<<1, 256, 0, stream>>>(A, B, E, cov, tp, c, Cg);
  kC<<<1, 64, 0, stream>>>(A, B, E, cov, tp, ini, Cg, Yg);
  kD<<<1, 256, 0, stream>>>(A, B, E, cov, tp, c, Yg, X);
  kE<<<blk, 256, 0, stream>>>(seq, A, B, E, cov, tp, X, out);
}

// Round 2
// 134.341 us; speedup vs baseline: 1.4976x; 1.4976x over previous
//
#include <hip/hip_runtime.h>
#include <math.h>

// Blocked parallel scan for a constant-coefficient 2-state affine recurrence.
// x_{t+1} = Trans x_t + XiCov dy_t + p0*cos(p1*t)*dt*[1,0];  out_t = Cout x_t.
// 3-kernel hierarchical affine scan: chunk offsets + block scan -> block
// aggregate scan -> reconstruct chunk starts + emit. All inter-chunk
// composition in fp64 using powers of P = Trans^L (they all commute).

constexpr int   TN  = 4000000;
constexpr float FDT = 1e-4f;
constexpr int   L   = 64;                  // steps per chunk
constexpr int   K   = TN / L;              // 62500 chunks
constexpr int   BT  = 256;                 // threads (=chunks) per block
constexpr int   NB  = (K + BT - 1) / BT;   // 245 blocks

struct Consts {
  float T00, T01, T10, T11;   // Trans
  float X00, X01, X10, X11;   // XiCov
  float C00, C01, C10, C11;   // Cout
  float p0, p1;
};

__device__ inline Consts make_consts(const float* __restrict__ A,
                                     const float* __restrict__ B,
                                     const float* __restrict__ E,
                                     const float* __restrict__ cov,
                                     const float* __restrict__ tp) {
  const float s2 = 1.41421356237309515f;  // sqrt(2)
  Consts c;
  float Xi[2][2];
  for (int i = 0; i < 2; ++i)
    for (int j = 0; j < 2; ++j)
      Xi[i][j] = (E[i*2+j] - (cov[i*2+0]*B[0*2+j] + cov[i*2+1]*B[1*2+j])) / s2;
  float XiC[2][2];
  for (int i = 0; i < 2; ++i)
    for (int j = 0; j < 2; ++j)
      XiC[i][j] = Xi[i][0]*(-s2*B[j*2+0]) + Xi[i][1]*(-s2*B[j*2+1]);
  c.T00 = 1.0f + (A[0] - XiC[0][0]) * FDT;
  c.T01 =        (A[1] - XiC[0][1]) * FDT;
  c.T10 =        (A[2] - XiC[1][0]) * FDT;
  c.T11 = 1.0f + (A[3] - XiC[1][1]) * FDT;
  c.X00 = Xi[0][0]; c.X01 = Xi[0][1]; c.X10 = Xi[1][0]; c.X11 = Xi[1][1];
  c.C00 = -s2 * B[0] * FDT;
  c.C01 = -s2 * B[2] * FDT;
  c.C10 = -s2 * B[1] * FDT;
  c.C11 = -s2 * B[3] * FDT;
  c.p0 = tp[0]; c.p1 = tp[1];
  return c;
}

__device__ inline void step(float& x0, float& x1, float t, float a, float b,
                            const Consts& c) {
  float u0 = fmaf(c.X00, a, fmaf(c.X01, b, c.p0 * __cosf(c.p1 * t) * FDT));
  float u1 = fmaf(c.X10, a, c.X11 * b);
  float n0 = fmaf(c.T00, x0, fmaf(c.T01, x1, u0));
  float n1 = fmaf(c.T10, x0, fmaf(c.T11, x1, u1));
  x0 = n0; x1 = n1;
}

__device__ inline void dsq(double* M) {
  double a = M[0]*M[0] + M[1]*M[2];
  double b = M[0]*M[1] + M[1]*M[3];
  double d = M[2]*M[0] + M[3]*M[2];
  double e = M[2]*M[1] + M[3]*M[3];
  M[0] = a; M[1] = b; M[2] = d; M[3] = e;
}

// Pw[i] = Trans^(L * 2^i), i = 0..n-1
__device__ inline void pow_table(const Consts& c, double (*Pw)[4], int n) {
  double M[4] = {(double)c.T00, (double)c.T01, (double)c.T10, (double)c.T11};
  for (int s = 0; s < 6; ++s) dsq(M);            // Trans^64 = Trans^L
  Pw[0][0] = M[0]; Pw[0][1] = M[1]; Pw[0][2] = M[2]; Pw[0][3] = M[3];
  for (int i = 1; i < n; ++i) {
    dsq(M);
    Pw[i][0] = M[0]; Pw[i][1] = M[1]; Pw[i][2] = M[2]; Pw[i][3] = M[3];
  }
}

// Phase 1: per-chunk offsets + in-block fp64 affine scan.
// Writes Xe[k] = exclusive-prefix offset within block (fp32 x2)
// and agg[b]   = inclusive full-block offset (fp64 x2).
__global__ void __launch_bounds__(BT)
k1(const float* __restrict__ seq, const float* __restrict__ A,
   const float* __restrict__ B, const float* __restrict__ E,
   const float* __restrict__ cov, const float* __restrict__ tp,
   float* __restrict__ Xe, double* __restrict__ agg) {
  const int tid  = threadIdx.x;
  const int lane = tid & 63;
  const int w    = tid >> 6;
  const int k    = blockIdx.x * BT + tid;
  Consts c = make_consts(A, B, E, cov, tp);

  float x0 = 0.f, x1 = 0.f;
  if (k < K) {
    const float4* p = (const float4*)(seq + (size_t)3 * L * k);  // 768B-aligned
    #pragma unroll 4
    for (int q = 0; q < L / 4; ++q) {
      float4 fa = p[3*q+0], fb = p[3*q+1], fc = p[3*q+2];
      step(x0, x1, fa.x, fa.y, fa.z, c);
      step(x0, x1, fa.w, fb.x, fb.y, c);
      step(x0, x1, fb.z, fb.w, fc.x, c);
      step(x0, x1, fc.y, fc.z, fc.w, c);
    }
  }

  double Pw[7][4];                 // P^(L*2^i), i=0..6 (P^L .. P^(64L))
  pow_table(c, Pw, 7);

  // wave-inclusive affine scan (offsets only; linear parts are uniform powers)
  double v0 = (double)x0, v1 = (double)x1;
  #pragma unroll
  for (int s = 0; s < 6; ++s) {
    int st = 1 << s;
    double p0 = __shfl_up(v0, st);
    double p1 = __shfl_up(v1, st);
    if (lane >= st) {
      double n0 = Pw[s][0]*p0 + Pw[s][1]*p1 + v0;
      double n1 = Pw[s][2]*p0 + Pw[s][3]*p1 + v1;
      v0 = n0; v1 = n1;
    }
  }

  __shared__ double wagg[4][2];
  if (lane == 63) { wagg[w][0] = v0; wagg[w][1] = v1; }
  __syncthreads();

  // exclusive prefix over preceding waves (<=3 fp64 mat-vecs)
  double E0 = 0.0, E1 = 0.0;
  for (int ww = 0; ww < w; ++ww) {
    double n0 = Pw[6][0]*E0 + Pw[6][1]*E1 + wagg[ww][0];
    double n1 = Pw[6][2]*E0 + Pw[6][3]*E1 + wagg[ww][1];
    E0 = n0; E1 = n1;
  }

  // wave-exclusive value
  double pv0 = __shfl_up(v0, 1);
  double pv1 = __shfl_up(v1, 1);
  if (lane == 0) { pv0 = 0.0; pv1 = 0.0; }

  // M = P^(lane*L) via binary decomposition (powers commute)
  double M0 = 1.0, M1 = 0.0, M2 = 0.0, M3 = 1.0;
  #pragma unroll
  for (int b = 0; b < 6; ++b) {
    if ((lane >> b) & 1) {
      double a0 = Pw[b][0]*M0 + Pw[b][1]*M2;
      double a1 = Pw[b][0]*M1 + Pw[b][1]*M3;
      double a2 = Pw[b][2]*M0 + Pw[b][3]*M2;
      double a3 = Pw[b][2]*M1 + Pw[b][3]*M3;
      M0 = a0; M1 = a1; M2 = a2; M3 = a3;
    }
  }

  double e0 = M0*E0 + M1*E1 + pv0;
  double e1 = M2*E0 + M3*E1 + pv1;
  if (k < K) {
    Xe[2*k]   = (float)e0;
    Xe[2*k+1] = (float)e1;
  }
  if (tid == BT - 1) {   // block-inclusive aggregate: P^(64L)*E_3 + v_incl
    agg[2*blockIdx.x]   = Pw[6][0]*E0 + Pw[6][1]*E1 + v0;
    agg[2*blockIdx.x+1] = Pw[6][2]*E0 + Pw[6][3]*E1 + v1;
  }
}

// Phase 2: single block scans NB block aggregates with Q = Trans^(BT*L).
__global__ void __launch_bounds__(BT)
k2(const float* __restrict__ A, const float* __restrict__ B,
   const float* __restrict__ E, const float* __restrict__ cov,
   const float* __restrict__ tp, const float* __restrict__ ini,
   const double* __restrict__ agg, double* __restrict__ Yb) {
  __shared__ double sA[2*NB];
  __shared__ double sY[2*NB];
  for (int i = threadIdx.x; i < 2*NB; i += BT) sA[i] = agg[i];
  __syncthreads();
  if (threadIdx.x == 0) {
    Consts c = make_consts(A, B, E, cov, tp);
    double Q[4] = {(double)c.T00, (double)c.T01, (double)c.T10, (double)c.T11};
    for (int s = 0; s < 14; ++s) dsq(Q);   // Trans^(256*64)
    double y0 = (double)ini[0], y1 = (double)ini[1];
    for (int b = 0; b < NB; ++b) {
      sY[2*b]   = y0;
      sY[2*b+1] = y1;
      double t0 = Q[0]*y0 + Q[1]*y1 + sA[2*b];
      double t1 = Q[2]*y0 + Q[3]*y1 + sA[2*b+1];
      y0 = t0; y1 = t1;
    }
  }
  __syncthreads();
  for (int i = threadIdx.x; i < 2*NB; i += BT) Yb[i] = sY[i];
}

// Phase 3: reconstruct chunk start X_k = P^(tid*L) * Yb[b] + Xe[k], emit.
__global__ void __launch_bounds__(BT)
k3(const float* __restrict__ seq, const float* __restrict__ A,
   const float* __restrict__ B, const float* __restrict__ E,
   const float* __restrict__ cov, const float* __restrict__ tp,
   const float* __restrict__ Xe, const double* __restrict__ Yb,
   float* __restrict__ out) {
  const int tid = threadIdx.x;
  const int k   = blockIdx.x * BT + tid;
  if (k >= K) return;
  Consts c = make_consts(A, B, E, cov, tp);

  double Pw[8][4];                 // P^L .. P^(128L)
  pow_table(c, Pw, 8);
  double M0 = 1.0, M1 = 0.0, M2 = 0.0, M3 = 1.0;
  #pragma unroll
  for (int b = 0; b < 8; ++b) {
    if ((tid >> b) & 1) {
      double a0 = Pw[b][0]*M0 + Pw[b][1]*M2;
      double a1 = Pw[b][0]*M1 + Pw[b][1]*M3;
      double a2 = Pw[b][2]*M0 + Pw[b][3]*M2;
      double a3 = Pw[b][2]*M1 + Pw[b][3]*M3;
      M0 = a0; M1 = a1; M2 = a2; M3 = a3;
    }
  }
  double y0 = Yb[2*blockIdx.x], y1 = Yb[2*blockIdx.x+1];
  float x0 = (float)(M0*y0 + M1*y1 + (double)Xe[2*k]);
  float x1 = (float)(M2*y0 + M3*y1 + (double)Xe[2*k+1]);

  const float4* p  = (const float4*)(seq + (size_t)3 * L * k);
  float4*       op = (float4*)(out + (size_t)2 * L * k);   // 512B-aligned
  #pragma unroll 4
  for (int q = 0; q < L / 4; ++q) {
    float4 fa = p[3*q+0], fb = p[3*q+1], fc = p[3*q+2];
    float4 oA, oB;
    oA.x = fmaf(c.C00, x0, c.C01 * x1); oA.y = fmaf(c.C10, x0, c.C11 * x1);
    step(x0, x1, fa.x, fa.y, fa.z, c);
    oA.z = fmaf(c.C00, x0, c.C01 * x1); oA.w = fmaf(c.C10, x0, c.C11 * x1);
    step(x0, x1, fa.w, fb.x, fb.y, c);
    oB.x = fmaf(c.C00, x0, c.C01 * x1); oB.y = fmaf(c.C10, x0, c.C11 * x1);
    step(x0, x1, fb.z, fb.w, fc.x, c);
    oB.z = fmaf(c.C00, x0, c.C01 * x1); oB.w = fmaf(c.C10, x0, c.C11 * x1);
    step(x0, x1, fc.y, fc.z, fc.w, c);
    op[2*q]   = oA;
    op[2*q+1] = oB;
  }
}

extern "C" void kernel_launch(void* const* d_in, const int* in_sizes, int n_in,
                              void* d_out, int out_size, void* d_ws, size_t ws_size,
                              hipStream_t stream) {
  const float* seq = (const float*)d_in[0];   // (1, T, 3)
  const float* A   = (const float*)d_in[1];
  const float* B   = (const float*)d_in[2];
  // d_in[3] = D, unused by the reference step
  const float* E   = (const float*)d_in[4];
  const float* cov = (const float*)d_in[5];
  const float* tp  = (const float*)d_in[6];
  const float* ini = (const float*)d_in[7];
  float* out = (float*)d_out;

  // workspace: Xe (2*K fp32 = 500000 B), agg (2*NB f64), Yb (2*NB f64)
  float*  Xe  = (float*)d_ws;
  double* agg = (double*)((char*)d_ws + 500224);   // 8B-aligned
  double* Yb  = agg + 2 * NB;

  k1<<<NB, BT, 0, stream>>>(seq, A, B, E, cov, tp, Xe, agg);
  k2<<<1,  BT, 0, stream>>>(A, B, E, cov, tp, ini, agg, Yb);
  k3<<<NB, BT, 0, stream>>>(seq, A, B, E, cov, tp, Xe, Yb, out);
}

// Round 3
// 126.975 us; speedup vs baseline: 1.5845x; 1.0580x over previous
//
#include <hip/hip_runtime.h>
#include <math.h>

// Blocked parallel scan for a constant-coefficient 2-state affine recurrence.
// x_{t+1} = Trans x_t + XiCov dy_t + p0*cos(p1*t)*dt*[1,0];  out_t = Cout x_t.
// L=16-step chunks so a 256-chunk block tile (48KB) fits in LDS: global
// traffic is fully coalesced float4, transposed through padded LDS rows.
// Inter-chunk composition in fp64 via commuting powers of P = Trans^L.

constexpr int   TN    = 4000000;
constexpr float FDT   = 1e-4f;
constexpr int   L     = 16;                  // steps per chunk
constexpr int   LOG2L = 4;
constexpr int   K     = TN / L;              // 250000 chunks
constexpr int   BT    = 256;                 // threads (=chunks) per block
constexpr int   NB    = (K + BT - 1) / BT;   // 977 blocks
constexpr int   ROW   = 13;                  // float4 per LDS chunk row (12 + pad)
constexpr int   F4IN  = TN * 3 / 4;          // 3,000,000 input float4
constexpr int   F4OUT = TN * 2 / 4;          // 2,000,000 output float4

struct Consts {
  float T00, T01, T10, T11;   // Trans
  float X00, X01, X10, X11;   // XiCov
  float C00, C01, C10, C11;   // Cout
  float p0, p1;
};

__device__ inline Consts make_consts(const float* __restrict__ A,
                                     const float* __restrict__ B,
                                     const float* __restrict__ E,
                                     const float* __restrict__ cov,
                                     const float* __restrict__ tp) {
  const float s2 = 1.41421356237309515f;  // sqrt(2)
  Consts c;
  float Xi[2][2];
  for (int i = 0; i < 2; ++i)
    for (int j = 0; j < 2; ++j)
      Xi[i][j] = (E[i*2+j] - (cov[i*2+0]*B[0*2+j] + cov[i*2+1]*B[1*2+j])) / s2;
  float XiC[2][2];
  for (int i = 0; i < 2; ++i)
    for (int j = 0; j < 2; ++j)
      XiC[i][j] = Xi[i][0]*(-s2*B[j*2+0]) + Xi[i][1]*(-s2*B[j*2+1]);
  c.T00 = 1.0f + (A[0] - XiC[0][0]) * FDT;
  c.T01 =        (A[1] - XiC[0][1]) * FDT;
  c.T10 =        (A[2] - XiC[1][0]) * FDT;
  c.T11 = 1.0f + (A[3] - XiC[1][1]) * FDT;
  c.X00 = Xi[0][0]; c.X01 = Xi[0][1]; c.X10 = Xi[1][0]; c.X11 = Xi[1][1];
  c.C00 = -s2 * B[0] * FDT;
  c.C01 = -s2 * B[2] * FDT;
  c.C10 = -s2 * B[1] * FDT;
  c.C11 = -s2 * B[3] * FDT;
  c.p0 = tp[0]; c.p1 = tp[1];
  return c;
}

__device__ inline void step(float& x0, float& x1, float t, float a, float b,
                            const Consts& c) {
  float u0 = fmaf(c.X00, a, fmaf(c.X01, b, c.p0 * __cosf(c.p1 * t) * FDT));
  float u1 = fmaf(c.X10, a, c.X11 * b);
  float n0 = fmaf(c.T00, x0, fmaf(c.T01, x1, u0));
  float n1 = fmaf(c.T10, x0, fmaf(c.T11, x1, u1));
  x0 = n0; x1 = n1;
}

__device__ inline void dsq(double* M) {
  double a = M[0]*M[0] + M[1]*M[2];
  double b = M[0]*M[1] + M[1]*M[3];
  double d = M[2]*M[0] + M[3]*M[2];
  double e = M[2]*M[1] + M[3]*M[3];
  M[0] = a; M[1] = b; M[2] = d; M[3] = e;
}

__device__ inline void dmm(const double* a, const double* b, double* o) {
  o[0] = a[0]*b[0] + a[1]*b[2];
  o[1] = a[0]*b[1] + a[1]*b[3];
  o[2] = a[2]*b[0] + a[3]*b[2];
  o[3] = a[2]*b[1] + a[3]*b[3];
}

// Pw[i] = Trans^(L * 2^i), i = 0..n-1
__device__ inline void pow_table(const Consts& c, double (*Pw)[4], int n) {
  double M[4] = {(double)c.T00, (double)c.T01, (double)c.T10, (double)c.T11};
  for (int s = 0; s < LOG2L; ++s) dsq(M);         // Trans^L
  Pw[0][0] = M[0]; Pw[0][1] = M[1]; Pw[0][2] = M[2]; Pw[0][3] = M[3];
  for (int i = 1; i < n; ++i) {
    dsq(M);
    Pw[i][0] = M[0]; Pw[i][1] = M[1]; Pw[i][2] = M[2]; Pw[i][3] = M[3];
  }
}

// Phase 1: coalesced stage -> LDS transpose -> per-chunk offsets -> block scan.
__global__ void __launch_bounds__(BT)
k1(const float* __restrict__ seq, const float* __restrict__ A,
   const float* __restrict__ B, const float* __restrict__ E,
   const float* __restrict__ cov, const float* __restrict__ tp,
   float2* __restrict__ Xe, double2* __restrict__ agg) {
  __shared__ float4  ls[BT * ROW];
  __shared__ double  wg[4][2];
  const int tid  = threadIdx.x;
  const int lane = tid & 63;
  const int w    = tid >> 6;
  const int k    = blockIdx.x * BT + tid;
  Consts c = make_consts(A, B, E, cov, tp);

  const float4* seq4 = (const float4*)seq;
  const size_t base = (size_t)blockIdx.x * (BT * 12);
  #pragma unroll
  for (int i = 0; i < 12; ++i) {
    int lf = i * BT + tid;
    size_t f = base + (size_t)lf;
    float4 v = make_float4(0.f, 0.f, 0.f, 0.f);
    if (f < (size_t)F4IN) v = seq4[f];
    int cc = lf / 12, s = lf - cc * 12;
    ls[cc * ROW + s] = v;
  }
  __syncthreads();

  float x0 = 0.f, x1 = 0.f;
  const float4* row = &ls[tid * ROW];
  #pragma unroll
  for (int q = 0; q < 4; ++q) {
    float4 fa = row[3*q], fb = row[3*q+1], fc = row[3*q+2];
    step(x0, x1, fa.x, fa.y, fa.z, c);
    step(x0, x1, fa.w, fb.x, fb.y, c);
    step(x0, x1, fb.z, fb.w, fc.x, c);
    step(x0, x1, fc.y, fc.z, fc.w, c);
  }

  double Pw[7][4];                 // P^(L*2^i), i=0..6
  pow_table(c, Pw, 7);

  // wave-inclusive affine scan (offsets; linear parts are uniform powers)
  double v0 = (double)x0, v1 = (double)x1;
  #pragma unroll
  for (int s = 0; s < 6; ++s) {
    int st = 1 << s;
    double p0 = __shfl_up(v0, st);
    double p1 = __shfl_up(v1, st);
    if (lane >= st) {
      double n0 = Pw[s][0]*p0 + Pw[s][1]*p1 + v0;
      double n1 = Pw[s][2]*p0 + Pw[s][3]*p1 + v1;
      v0 = n0; v1 = n1;
    }
  }
  if (lane == 63) { wg[w][0] = v0; wg[w][1] = v1; }
  __syncthreads();

  double E0 = 0.0, E1 = 0.0;
  for (int ww = 0; ww < w; ++ww) {
    double n0 = Pw[6][0]*E0 + Pw[6][1]*E1 + wg[ww][0];
    double n1 = Pw[6][2]*E0 + Pw[6][3]*E1 + wg[ww][1];
    E0 = n0; E1 = n1;
  }

  double pv0 = __shfl_up(v0, 1);
  double pv1 = __shfl_up(v1, 1);
  if (lane == 0) { pv0 = 0.0; pv1 = 0.0; }

  // M = P^(lane*L)
  double M0 = 1.0, M1 = 0.0, M2 = 0.0, M3 = 1.0;
  #pragma unroll
  for (int b = 0; b < 6; ++b) {
    if ((lane >> b) & 1) {
      double a0 = Pw[b][0]*M0 + Pw[b][1]*M2;
      double a1 = Pw[b][0]*M1 + Pw[b][1]*M3;
      double a2 = Pw[b][2]*M0 + Pw[b][3]*M2;
      double a3 = Pw[b][2]*M1 + Pw[b][3]*M3;
      M0 = a0; M1 = a1; M2 = a2; M3 = a3;
    }
  }
  double e0 = M0*E0 + M1*E1 + pv0;
  double e1 = M2*E0 + M3*E1 + pv1;
  if (k < K) Xe[k] = make_float2((float)e0, (float)e1);
  if (tid == BT - 1) {
    double a0 = Pw[6][0]*E0 + Pw[6][1]*E1 + v0;
    double a1 = Pw[6][2]*E0 + Pw[6][3]*E1 + v1;
    agg[blockIdx.x] = make_double2(a0, a1);
  }
}

// Phase 2: parallel affine scan over NB block aggregates (Q = Trans^(BT*L)).
// Initial state folded in as virtual element 0; Yb[i] = start state of block i.
__global__ void __launch_bounds__(BT)
k2(const float* __restrict__ A, const float* __restrict__ B,
   const float* __restrict__ E, const float* __restrict__ cov,
   const float* __restrict__ tp, const float* __restrict__ ini,
   const double2* __restrict__ agg, double2* __restrict__ Yb) {
  __shared__ double wg[4][2];
  const int tid = threadIdx.x, lane = tid & 63, w = tid >> 6;
  Consts c = make_consts(A, B, E, cov, tp);

  double Q[4] = {(double)c.T00, (double)c.T01, (double)c.T10, (double)c.T11};
  for (int s = 0; s < LOG2L + 8; ++s) dsq(Q);   // Trans^(L*BT) = Trans^4096
  double Q2[4], Q3[4], Q4[4];
  dmm(Q, Q, Q2); dmm(Q2, Q, Q3); dmm(Q2, Q2, Q4);
  double QW[7][4];                               // Q^(4*2^s), s=0..6
  for (int i = 0; i < 4; ++i) QW[0][i] = Q4[i];
  for (int s = 1; s < 7; ++s) dmm(QW[s-1], QW[s-1], QW[s]);

  // 4 elements per thread; element 0 is the initial state.
  double i0 = 0.0, i1 = 0.0;
  double inc[4][2];
  #pragma unroll
  for (int j = 0; j < 4; ++j) {
    int idx = 4 * tid + j;
    double e0 = 0.0, e1 = 0.0;
    if (idx == 0)      { e0 = (double)ini[0]; e1 = (double)ini[1]; }
    else if (idx < NB) { double2 a = agg[idx-1]; e0 = a.x; e1 = a.y; }
    double n0 = Q[0]*i0 + Q[1]*i1 + e0;
    double n1 = Q[2]*i0 + Q[3]*i1 + e1;
    i0 = n0; i1 = n1;
    inc[j][0] = i0; inc[j][1] = i1;
  }

  double v0 = i0, v1 = i1;
  #pragma unroll
  for (int s = 0; s < 6; ++s) {
    int st = 1 << s;
    double p0 = __shfl_up(v0, st);
    double p1 = __shfl_up(v1, st);
    if (lane >= st) {
      double n0 = QW[s][0]*p0 + QW[s][1]*p1 + v0;
      double n1 = QW[s][2]*p0 + QW[s][3]*p1 + v1;
      v0 = n0; v1 = n1;
    }
  }
  if (lane == 63) { wg[w][0] = v0; wg[w][1] = v1; }
  __syncthreads();
  double E0 = 0.0, E1 = 0.0;
  for (int ww = 0; ww < w; ++ww) {
    double n0 = QW[6][0]*E0 + QW[6][1]*E1 + wg[ww][0];
    double n1 = QW[6][2]*E0 + QW[6][3]*E1 + wg[ww][1];
    E0 = n0; E1 = n1;
  }
  double pv0 = __shfl_up(v0, 1);
  double pv1 = __shfl_up(v1, 1);
  if (lane == 0) { pv0 = 0.0; pv1 = 0.0; }

  double M0 = 1.0, M1 = 0.0, M2 = 0.0, M3 = 1.0;   // Q^(4*lane)
  #pragma unroll
  for (int b = 0; b < 6; ++b) {
    if ((lane >> b) & 1) {
      double a0 = QW[b][0]*M0 + QW[b][1]*M2;
      double a1 = QW[b][0]*M1 + QW[b][1]*M3;
      double a2 = QW[b][2]*M0 + QW[b][3]*M2;
      double a3 = QW[b][2]*M1 + QW[b][3]*M3;
      M0 = a0; M1 = a1; M2 = a2; M3 = a3;
    }
  }
  double Eth0 = M0*E0 + M1*E1 + pv0;
  double Eth1 = M2*E0 + M3*E1 + pv1;

  const double* Pj[4] = {Q, Q2, Q3, Q4};   // Q^(j+1)
  #pragma unroll
  for (int j = 0; j < 4; ++j) {
    int idx = 4 * tid + j;
    if (idx < NB) {
      double y0 = Pj[j][0]*Eth0 + Pj[j][1]*Eth1 + inc[j][0];
      double y1 = Pj[j][2]*Eth0 + Pj[j][3]*Eth1 + inc[j][1];
      Yb[idx] = make_double2(y0, y1);
    }
  }
}

// Phase 3: reconstruct chunk starts, emit outputs via in-place LDS transpose.
__global__ void __launch_bounds__(BT)
k3(const float* __restrict__ seq, const float* __restrict__ A,
   const float* __restrict__ B, const float* __restrict__ E,
   const float* __restrict__ cov, const float* __restrict__ tp,
   const float2* __restrict__ Xe, const double2* __restrict__ Yb,
   float* __restrict__ out) {
  __shared__ float4 ls[BT * ROW];
  const int tid = threadIdx.x;
  const int k   = blockIdx.x * BT + tid;
  Consts c = make_consts(A, B, E, cov, tp);

  const float4* seq4 = (const float4*)seq;
  const size_t base = (size_t)blockIdx.x * (BT * 12);
  #pragma unroll
  for (int i = 0; i < 12; ++i) {
    int lf = i * BT + tid;
    size_t f = base + (size_t)lf;
    float4 v = make_float4(0.f, 0.f, 0.f, 0.f);
    if (f < (size_t)F4IN) v = seq4[f];
    int cc = lf / 12, s = lf - cc * 12;
    ls[cc * ROW + s] = v;
  }
  __syncthreads();

  double Pw[8][4];                 // P^L .. P^(128L)
  pow_table(c, Pw, 8);
  double M0 = 1.0, M1 = 0.0, M2 = 0.0, M3 = 1.0;   // P^(tid*L)
  #pragma unroll
  for (int b = 0; b < 8; ++b) {
    if ((tid >> b) & 1) {
      double a0 = Pw[b][0]*M0 + Pw[b][1]*M2;
      double a1 = Pw[b][0]*M1 + Pw[b][1]*M3;
      double a2 = Pw[b][2]*M0 + Pw[b][3]*M2;
      double a3 = Pw[b][2]*M1 + Pw[b][3]*M3;
      M0 = a0; M1 = a1; M2 = a2; M3 = a3;
    }
  }
  double2 yb = Yb[blockIdx.x];
  float2 xe = (k < K) ? Xe[k] : make_float2(0.f, 0.f);
  float x0 = (float)(M0*yb.x + M1*yb.y + (double)xe.x);
  float x1 = (float)(M2*yb.x + M3*yb.y + (double)xe.y);

  float4* row = &ls[tid * ROW];
  #pragma unroll
  for (int q = 0; q < 4; ++q) {
    float4 fa = row[3*q], fb = row[3*q+1], fc = row[3*q+2];
    float4 oA, oB;
    oA.x = fmaf(c.C00, x0, c.C01 * x1); oA.y = fmaf(c.C10, x0, c.C11 * x1);
    step(x0, x1, fa.x, fa.y, fa.z, c);
    oA.z = fmaf(c.C00, x0, c.C01 * x1); oA.w = fmaf(c.C10, x0, c.C11 * x1);
    step(x0, x1, fa.w, fb.x, fb.y, c);
    oB.x = fmaf(c.C00, x0, c.C01 * x1); oB.y = fmaf(c.C10, x0, c.C11 * x1);
    step(x0, x1, fb.z, fb.w, fc.x, c);
    oB.z = fmaf(c.C00, x0, c.C01 * x1); oB.w = fmaf(c.C10, x0, c.C11 * x1);
    step(x0, x1, fc.y, fc.z, fc.w, c);
    row[2*q]   = oA;   // in-place: slot 2q   <= consumed input slot 3q
    row[2*q+1] = oB;   //           slot 2q+1 <= consumed input slot 3q+2
  }
  __syncthreads();

  float4* out4 = (float4*)out;
  const size_t obase = (size_t)blockIdx.x * (BT * 8);
  #pragma unroll
  for (int i = 0; i < 8; ++i) {
    int lf = i * BT + tid;
    size_t g = obase + (size_t)lf;
    if (g < (size_t)F4OUT) {
      int cc = lf >> 3, s = lf & 7;
      out4[g] = ls[cc * ROW + s];
    }
  }
}

extern "C" void kernel_launch(void* const* d_in, const int* in_sizes, int n_in,
                              void* d_out, int out_size, void* d_ws, size_t ws_size,
                              hipStream_t stream) {
  const float* seq = (const float*)d_in[0];   // (1, T, 3)
  const float* A   = (const float*)d_in[1];
  const float* B   = (const float*)d_in[2];
  // d_in[3] = D, unused by the reference step
  const float* E   = (const float*)d_in[4];
  const float* cov = (const float*)d_in[5];
  const float* tp  = (const float*)d_in[6];
  const float* ini = (const float*)d_in[7];
  float* out = (float*)d_out;

  // workspace: Xe (K float2 = 2,000,000 B), agg (NB double2), Yb (NB double2)
  float2*  Xe  = (float2*)d_ws;
  double2* agg = (double2*)((char*)d_ws + 2000000);
  double2* Yb  = (double2*)((char*)d_ws + 2000000 + 16384);

  k1<<<NB, BT, 0, stream>>>(seq, A, B, E, cov, tp, Xe, agg);
  k2<<<1,  BT, 0, stream>>>(A, B, E, cov, tp, ini, agg, Yb);
  k3<<<NB, BT, 0, stream>>>(seq, A, B, E, cov, tp, Xe, Yb, out);
}